// Round 9
// baseline (171.495 us; speedup 1.0000x reference)
//
#include <hip/hip_runtime.h>

// GraphUnpoolingMesh, output layout (flat f32):
//   [ new_x : (N+E)*F | ei_row0 : M | ei_row1 : M ],  M = 3E + 3T
//
// R8: XCD-affine src-bucketed gather won 146->136 us. R9: protect the src
// bucket's L2 residency (nt loads on all single-use streams: dst gather,
// tuples, copy reads), drop the slot-init pass (validity = fill count from
// final cursor), pack tuples to 8B. Machinery traffic -26 MB.

#define F 128
#define F4 32                    // float4 per row
#define BSHIFT 10                // 1024 nodes / bucket = 0.5 MB of x
#define SLOTS 8192               // slots per bucket (mean fill 6144, 26 sigma)
#define SPB_BLOCKS (SLOTS / 16)  // midpoint blocks per bucket (16 slots/block)
#define CHUNK 2048               // edges per scatter block

typedef float f32x4 __attribute__((ext_vector_type(4)));
typedef unsigned long long u64;

__device__ __forceinline__ void nt_store4(f32x4 v, f32x4* p) {
    asm volatile("global_store_dwordx4 %0, %1, off sc0 sc1 nt"
                 :: "v"(p), "v"(v) : "memory");
}
__device__ __forceinline__ void nt_store1(float v, float* p) {
    asm volatile("global_store_dword %0, %1, off sc0 sc1 nt"
                 :: "v"(p), "v"(v) : "memory");
}

// K1: init per-bucket cursors only (98 ints).
__global__ void init_kernel(int* __restrict__ cursor, int NB) {
    const int t = threadIdx.x;
    if (t < NB) cursor[t] = t * SLOTS;
}

// K2: two-phase LDS-aggregated scatter into per-bucket slot regions.
// Tuple = (pk<<32)|dst with pk = e | (src&1023)<<20  (src = bucket<<10 | low).
__global__ __launch_bounds__(256) void scatter_kernel(
        const int* __restrict__ ei0, const int* __restrict__ ei1,
        int* __restrict__ cursor, u64* __restrict__ tup, int E, int NB) {
    __shared__ int lh[128];
    __shared__ int lbase[128];
    const int t = threadIdx.x;
    if (t < 128) lh[t] = 0;
    __syncthreads();
    const int base = blockIdx.x * CHUNK;
    int s[8], d[8], bk[8], rk[8];
#pragma unroll
    for (int i = 0; i < 8; ++i) {
        const int e = base + i * 256 + t;
        if (e < E) {
            s[i] = ei0[e];
            d[i] = ei1[e];
            bk[i] = s[i] >> BSHIFT;
            rk[i] = atomicAdd(&lh[bk[i]], 1);
        } else {
            bk[i] = -1;
        }
    }
    __syncthreads();
    if (t < NB) {
        const int c = lh[t];
        lbase[t] = c ? atomicAdd(&cursor[t], c) : 0;
    }
    __syncthreads();
#pragma unroll
    for (int i = 0; i < 8; ++i) {
        if (bk[i] >= 0) {
            const int e = base + i * 256 + t;
            const int pos = lbase[bk[i]] + rk[i];
            if (pos < (bk[i] + 1) * SLOTS) {      // overflow guard (26-sigma)
                const u64 pk = (u64)(e | ((s[i] & 1023) << 20));
                __builtin_nontemporal_store((pk << 32) | (unsigned)d[i], &tup[pos]);
            }
        }
    }
}

// K3: fused main. Grid = [MB midpoint | EBlk edge-rows | CB copy].
__global__ __launch_bounds__(256) void main_kernel(
        const f32x4* __restrict__ x4,
        const int* __restrict__ ei0, const int* __restrict__ ei1,
        const u64* __restrict__ tup, const int* __restrict__ cursor,
        f32x4* __restrict__ out4, float* __restrict__ r0, float* __restrict__ r1,
        int N, int E, int M, int NB, int MB, int EBlk) {
    const unsigned b = blockIdx.x;

    if (b < (unsigned)MB) {
        // ---- midpoints, XCD-affine bucket sweep ----
        const int xcd = b & 7;
        const int seq = b >> 3;
        const int bucket = xcd + 8 * (seq / SPB_BLOCKS);
        if (bucket >= NB) return;
        const int cnt = cursor[bucket] - bucket * SLOTS;  // fill count
        const int chunk = seq % SPB_BLOCKS;
        const int si0 = chunk * 16 + (threadIdx.x >> 5) * 2;
        if (si0 >= cnt) return;
        const int lane = threadIdx.x & 31;
        const int p0 = bucket * SLOTS + si0;
        const int nbase = bucket << BSHIFT;

        const u64 t0 = __builtin_nontemporal_load(&tup[p0]);
        const bool have1 = (si0 + 1) < cnt;
        const u64 t1 = have1 ? __builtin_nontemporal_load(&tup[p0 + 1]) : 0;

        const int d0 = (int)(t0 & 0xffffffffu);
        const int pk0 = (int)(t0 >> 32);
        const int s0 = nbase | (pk0 >> 20);
        const int e0 = pk0 & 0xFFFFF;

        // src: normal load (L2-resident bucket). dst: nt (single-use stream).
        f32x4 a0 = x4[(size_t)s0 * F4 + lane];
        f32x4 b0 = __builtin_nontemporal_load(&x4[(size_t)d0 * F4 + lane]);

        if (have1) {
            const int d1 = (int)(t1 & 0xffffffffu);
            const int pk1 = (int)(t1 >> 32);
            const int s1 = nbase | (pk1 >> 20);
            const int e1 = pk1 & 0xFFFFF;
            f32x4 a1 = x4[(size_t)s1 * F4 + lane];
            f32x4 b1 = __builtin_nontemporal_load(&x4[(size_t)d1 * F4 + lane]);
            nt_store4(0.5f * (a0 + b0), &out4[(size_t)(N + e0) * F4 + lane]);
            nt_store4(0.5f * (a1 + b1), &out4[(size_t)(N + e1) * F4 + lane]);
        } else {
            nt_store4(0.5f * (a0 + b0), &out4[(size_t)(N + e0) * F4 + lane]);
        }
        return;
    }

    const unsigned eb = b - MB;
    if (eb < (unsigned)EBlk) {
        // ---- edge-index rows ----
        const int col = eb * 256 + threadIdx.x;
        if (col >= M) return;
        int a, c;
        if (col < E) {
            a = ei0[col];
            c = ei1[col];
        } else if (col < 2 * E) {
            const int e = col - E;
            a = ei0[e];
            c = N + e;
        } else if (col < 3 * E) {
            const int e = col - 2 * E;
            a = N + e;
            c = ei1[e];
        } else {
            const int j = col - 3 * E;
            const int tt = j / 3;
            const int k = j - 3 * tt;
            const int i = N + 3 * tt;
            a = i + k;
            c = (k < 2) ? (i + k + 1) : i;
        }
        nt_store1((float)a, &r0[col]);
        nt_store1((float)c, &r1[col]);
        return;
    }

    // ---- copy rows (tail of grid; nt reads keep L2 clean for midpoints) ----
    const unsigned cb = eb - EBlk;
    const int lane = threadIdx.x & 31;
    const int g = threadIdx.x >> 5;
    const long long row0 = (long long)cb * 16 + g * 2;
    if (row0 < N) {
        f32x4 v0 = __builtin_nontemporal_load(&x4[row0 * F4 + lane]);
        nt_store4(v0, &out4[row0 * F4 + lane]);
    }
    const long long row1 = row0 + 1;
    if (row1 < N) {
        f32x4 v1 = __builtin_nontemporal_load(&x4[row1 * F4 + lane]);
        nt_store4(v1, &out4[row1 * F4 + lane]);
    }
}

extern "C" void kernel_launch(void* const* d_in, const int* in_sizes, int n_in,
                              void* d_out, int out_size, void* d_ws, size_t ws_size,
                              hipStream_t stream) {
    const float* x = (const float*)d_in[0];
    const int* ei = (const int*)d_in[1];

    const int N = in_sizes[0] / F;                 // 100000
    const int E = in_sizes[1] / 2;                 // 600000
    const int T = (E > 2) ? (E - 2 + 2) / 3 : 0;   // ceil((E-2)/3)
    const int M = 3 * E + 3 * T;

    const int* ei0 = ei;
    const int* ei1 = ei + E;

    float* out = (float*)d_out;
    float* r0 = out + (size_t)(N + E) * F;
    float* r1 = r0 + M;

    // ws layout: [0..4095] cursors | [4096..] u64 slot array
    int* cursor = (int*)d_ws;
    u64* tup = (u64*)((char*)d_ws + 4096);

    const int NB = (N + (1 << BSHIFT) - 1) >> BSHIFT;   // 98
    const int NBpad = (NB + 7) & ~7;                    // 104
    const int MB = NBpad * SPB_BLOCKS;                  // 53248 midpoint blocks
    const int EBlk = (M + 255) / 256;                   // 9375
    const int CB = (N + 15) / 16;                       // 6250

    init_kernel<<<1, 128, 0, stream>>>(cursor, NB);
    scatter_kernel<<<(E + CHUNK - 1) / CHUNK, 256, 0, stream>>>(
        ei0, ei1, cursor, tup, E, NB);
    main_kernel<<<MB + EBlk + CB, 256, 0, stream>>>(
        (const f32x4*)x, ei0, ei1, tup, cursor, (f32x4*)out, r0, r1,
        N, E, M, NB, MB, EBlk);
}

// Round 10
// 133.690 us; speedup vs baseline: 1.2828x; 1.2828x over previous
//
#include <hip/hip_runtime.h>

// GraphUnpoolingMesh, output layout (flat f32):
//   [ new_x : (N+E)*F | ei_row0 : M | ei_row1 : M ],  M = 3E + 3T
//
// R8 (136us): XCD-affine src-bucketed gather. R9 (171us, REGRESSION):
// nontemporal LOADS bypass L2+L3 -> dst gather lost all cache service.
// Lesson: nt stores neutral, nt loads harmful. R10 = R8 structure with
// normal loads everywhere + machinery slimming only (8B tuples, no
// slot-init pass; validity via cursor fill counts). -22 MB traffic vs R8.

#define F 128
#define F4 32                    // float4 per row
#define BSHIFT 10                // 1024 nodes / bucket = 0.5 MB of x
#define SLOTS 8192               // slots per bucket (mean fill 6144, 26 sigma)
#define SPB_BLOCKS (SLOTS / 16)  // midpoint blocks per bucket (16 slots/block)
#define CHUNK 2048               // edges per scatter block

typedef float f32x4 __attribute__((ext_vector_type(4)));
typedef unsigned long long u64;

__device__ __forceinline__ void nt_store4(f32x4 v, f32x4* p) {
    asm volatile("global_store_dwordx4 %0, %1, off sc0 sc1 nt"
                 :: "v"(p), "v"(v) : "memory");
}
__device__ __forceinline__ void nt_store1(float v, float* p) {
    asm volatile("global_store_dword %0, %1, off sc0 sc1 nt"
                 :: "v"(p), "v"(v) : "memory");
}

// K1: init per-bucket cursors only (98 ints).
__global__ void init_kernel(int* __restrict__ cursor, int NB) {
    const int t = threadIdx.x;
    if (t < NB) cursor[t] = t * SLOTS;
}

// K2: two-phase LDS-aggregated scatter into per-bucket slot regions.
// Tuple = (pk<<32)|dst with pk = e | (src&1023)<<20  (src = bucket<<10 | low).
__global__ __launch_bounds__(256) void scatter_kernel(
        const int* __restrict__ ei0, const int* __restrict__ ei1,
        int* __restrict__ cursor, u64* __restrict__ tup, int E, int NB) {
    __shared__ int lh[128];
    __shared__ int lbase[128];
    const int t = threadIdx.x;
    if (t < 128) lh[t] = 0;
    __syncthreads();
    const int base = blockIdx.x * CHUNK;
    int s[8], d[8], bk[8], rk[8];
#pragma unroll
    for (int i = 0; i < 8; ++i) {
        const int e = base + i * 256 + t;
        if (e < E) {
            s[i] = ei0[e];
            d[i] = ei1[e];
            bk[i] = s[i] >> BSHIFT;
            rk[i] = atomicAdd(&lh[bk[i]], 1);
        } else {
            bk[i] = -1;
        }
    }
    __syncthreads();
    if (t < NB) {
        const int c = lh[t];
        lbase[t] = c ? atomicAdd(&cursor[t], c) : 0;
    }
    __syncthreads();
#pragma unroll
    for (int i = 0; i < 8; ++i) {
        if (bk[i] >= 0) {
            const int e = base + i * 256 + t;
            const int pos = lbase[bk[i]] + rk[i];
            if (pos < (bk[i] + 1) * SLOTS) {      // overflow guard (26-sigma)
                const u64 pk = (u64)(e | ((s[i] & 1023) << 20));
                tup[pos] = (pk << 32) | (unsigned)d[i];
            }
        }
    }
}

// K3: fused main. Grid = [MB midpoint | EBlk edge-rows | CB copy].
__global__ __launch_bounds__(256) void main_kernel(
        const f32x4* __restrict__ x4,
        const int* __restrict__ ei0, const int* __restrict__ ei1,
        const u64* __restrict__ tup, const int* __restrict__ cursor,
        f32x4* __restrict__ out4, float* __restrict__ r0, float* __restrict__ r1,
        int N, int E, int M, int NB, int MB, int EBlk) {
    const unsigned b = blockIdx.x;

    if (b < (unsigned)MB) {
        // ---- midpoints, XCD-affine bucket sweep ----
        const int xcd = b & 7;
        const int seq = b >> 3;
        const int bucket = xcd + 8 * (seq / SPB_BLOCKS);
        if (bucket >= NB) return;
        const int cnt = cursor[bucket] - bucket * SLOTS;  // fill count
        const int chunk = seq % SPB_BLOCKS;
        const int si0 = chunk * 16 + (threadIdx.x >> 5) * 2;
        if (si0 >= cnt) return;
        const int lane = threadIdx.x & 31;
        const int p0 = bucket * SLOTS + si0;
        const int nbase = bucket << BSHIFT;

        const u64 t0 = tup[p0];
        const bool have1 = (si0 + 1) < cnt;
        const u64 t1 = have1 ? tup[p0 + 1] : 0;

        const int d0 = (int)(t0 & 0xffffffffu);
        const int pk0 = (int)(t0 >> 32);
        const int s0 = nbase | (pk0 >> 20);
        const int e0 = pk0 & 0xFFFFF;

        f32x4 a0 = x4[(size_t)s0 * F4 + lane];    // src: L2-resident bucket
        f32x4 b0 = x4[(size_t)d0 * F4 + lane];    // dst: random (L2/L3 help)

        if (have1) {
            const int d1 = (int)(t1 & 0xffffffffu);
            const int pk1 = (int)(t1 >> 32);
            const int s1 = nbase | (pk1 >> 20);
            const int e1 = pk1 & 0xFFFFF;
            f32x4 a1 = x4[(size_t)s1 * F4 + lane];
            f32x4 b1 = x4[(size_t)d1 * F4 + lane];
            nt_store4(0.5f * (a0 + b0), &out4[(size_t)(N + e0) * F4 + lane]);
            nt_store4(0.5f * (a1 + b1), &out4[(size_t)(N + e1) * F4 + lane]);
        } else {
            nt_store4(0.5f * (a0 + b0), &out4[(size_t)(N + e0) * F4 + lane]);
        }
        return;
    }

    const unsigned eb = b - MB;
    if (eb < (unsigned)EBlk) {
        // ---- edge-index rows ----
        const int col = eb * 256 + threadIdx.x;
        if (col >= M) return;
        int a, c;
        if (col < E) {
            a = ei0[col];
            c = ei1[col];
        } else if (col < 2 * E) {
            const int e = col - E;
            a = ei0[e];
            c = N + e;
        } else if (col < 3 * E) {
            const int e = col - 2 * E;
            a = N + e;
            c = ei1[e];
        } else {
            const int j = col - 3 * E;
            const int tt = j / 3;
            const int k = j - 3 * tt;
            const int i = N + 3 * tt;
            a = i + k;
            c = (k < 2) ? (i + k + 1) : i;
        }
        nt_store1((float)a, &r0[col]);
        nt_store1((float)c, &r1[col]);
        return;
    }

    // ---- copy rows (tail of grid) ----
    const unsigned cb = eb - EBlk;
    const int lane = threadIdx.x & 31;
    const int g = threadIdx.x >> 5;
    const long long row0 = (long long)cb * 16 + g * 2;
    if (row0 < N) {
        f32x4 v0 = x4[row0 * F4 + lane];
        nt_store4(v0, &out4[row0 * F4 + lane]);
    }
    const long long row1 = row0 + 1;
    if (row1 < N) {
        f32x4 v1 = x4[row1 * F4 + lane];
        nt_store4(v1, &out4[row1 * F4 + lane]);
    }
}

extern "C" void kernel_launch(void* const* d_in, const int* in_sizes, int n_in,
                              void* d_out, int out_size, void* d_ws, size_t ws_size,
                              hipStream_t stream) {
    const float* x = (const float*)d_in[0];
    const int* ei = (const int*)d_in[1];

    const int N = in_sizes[0] / F;                 // 100000
    const int E = in_sizes[1] / 2;                 // 600000
    const int T = (E > 2) ? (E - 2 + 2) / 3 : 0;   // ceil((E-2)/3)
    const int M = 3 * E + 3 * T;

    const int* ei0 = ei;
    const int* ei1 = ei + E;

    float* out = (float*)d_out;
    float* r0 = out + (size_t)(N + E) * F;
    float* r1 = r0 + M;

    // ws layout: [0..4095] cursors | [4096..] u64 slot array
    int* cursor = (int*)d_ws;
    u64* tup = (u64*)((char*)d_ws + 4096);

    const int NB = (N + (1 << BSHIFT) - 1) >> BSHIFT;   // 98
    const int NBpad = (NB + 7) & ~7;                    // 104
    const int MB = NBpad * SPB_BLOCKS;                  // 53248 midpoint blocks
    const int EBlk = (M + 255) / 256;                   // 9375
    const int CB = (N + 15) / 16;                       // 6250

    init_kernel<<<1, 128, 0, stream>>>(cursor, NB);
    scatter_kernel<<<(E + CHUNK - 1) / CHUNK, 256, 0, stream>>>(
        ei0, ei1, cursor, tup, E, NB);
    main_kernel<<<MB + EBlk + CB, 256, 0, stream>>>(
        (const f32x4*)x, ei0, ei1, tup, cursor, (f32x4*)out, r0, r1,
        N, E, M, NB, MB, EBlk);
}

// Round 11
// 126.456 us; speedup vs baseline: 1.3562x; 1.0572x over previous
//
#include <hip/hip_runtime.h>

// GraphUnpoolingMesh, output layout (flat f32):
//   [ new_x : (N+E)*F | ei_row0 : M | ei_row1 : M ],  M = 3E + 3T
//
// Ladder: 153 (naive) -> 146 -> 136 (R8 XCD-affine src buckets) -> 133.7
// (R10 slim machinery). R10 analysis: main kernel ~803 MB @ 6.7 TB/s = 97%
// of the 6.9 TB/s empirical ceiling -> only byte-removal helps.
// R11: (1) fold node-copy into the bucket sweep (bucket rows are L2-hot
// from the src gathers -> copy reads become L2 hits, -51 MB HBM);
// (2) fold edge-row emission into scatter (s,d,e already in registers,
// -9.6 MB ei re-read; tri cols are arithmetic, 3T <= E so same grid).

#define F 128
#define F4 32                    // float4 per row
#define BSHIFT 10                // 1024 nodes / bucket = 0.5 MB of x
#define SLOTS 8192               // slots per bucket (mean fill 6144, 26 sigma)
#define SPB 512                  // slot-chunks per bucket (16 slots/block)
#define CPB 64                   // copy-chunks per bucket (16 rows/block)
#define BPB (SPB + CPB)          // blocks per bucket = 576
#define CHUNK 2048               // edges per scatter block

typedef float f32x4 __attribute__((ext_vector_type(4)));
typedef unsigned long long u64;

__device__ __forceinline__ void nt_store4(f32x4 v, f32x4* p) {
    asm volatile("global_store_dwordx4 %0, %1, off sc0 sc1 nt"
                 :: "v"(p), "v"(v) : "memory");
}
__device__ __forceinline__ void nt_store1(float v, float* p) {
    asm volatile("global_store_dword %0, %1, off sc0 sc1 nt"
                 :: "v"(p), "v"(v) : "memory");
}

// K1: init per-bucket cursors only (98 ints).
__global__ void init_kernel(int* __restrict__ cursor, int NB) {
    const int t = threadIdx.x;
    if (t < NB) cursor[t] = t * SLOTS;
}

// K2: scatter edges into bucket slot regions + emit ALL edge-index rows.
// Tuple = (pk<<32)|dst with pk = e | (src&1023)<<20  (src = bucket<<10 | low).
__global__ __launch_bounds__(256) void scatter_kernel(
        const int* __restrict__ ei0, const int* __restrict__ ei1,
        int* __restrict__ cursor, u64* __restrict__ tup,
        float* __restrict__ r0, float* __restrict__ r1,
        int N, int E, int TT3, int NB) {
    __shared__ int lh[128];
    __shared__ int lbase[128];
    const int t = threadIdx.x;
    if (t < 128) lh[t] = 0;
    __syncthreads();
    const int base = blockIdx.x * CHUNK;
    int s[8], d[8], bk[8], rk[8];
#pragma unroll
    for (int i = 0; i < 8; ++i) {
        const int e = base + i * 256 + t;
        if (e < E) {
            s[i] = ei0[e];
            d[i] = ei1[e];
            bk[i] = s[i] >> BSHIFT;
            rk[i] = atomicAdd(&lh[bk[i]], 1);
            // edge-index rows for this edge (orig, src->mid, mid->dst)
            const float fs = (float)s[i], fd = (float)d[i], fm = (float)(N + e);
            nt_store1(fs, &r0[e]);
            nt_store1(fd, &r1[e]);
            nt_store1(fs, &r0[E + e]);
            nt_store1(fm, &r1[E + e]);
            nt_store1(fm, &r0[2 * E + e]);
            nt_store1(fd, &r1[2 * E + e]);
        } else {
            bk[i] = -1;
        }
        // triangle cols (3T <= E, same index space)
        if (e < TT3) {
            const int tt = e / 3;
            const int k = e - 3 * tt;
            const int ii = N + 3 * tt;
            nt_store1((float)(ii + k), &r0[3 * E + e]);
            nt_store1((float)((k < 2) ? (ii + k + 1) : ii), &r1[3 * E + e]);
        }
    }
    __syncthreads();
    if (t < NB) {
        const int c = lh[t];
        lbase[t] = c ? atomicAdd(&cursor[t], c) : 0;
    }
    __syncthreads();
#pragma unroll
    for (int i = 0; i < 8; ++i) {
        if (bk[i] >= 0) {
            const int e = base + i * 256 + t;
            const int pos = lbase[bk[i]] + rk[i];
            if (pos < (bk[i] + 1) * SLOTS) {      // overflow guard (26-sigma)
                const u64 pk = (u64)(e | ((s[i] & 1023) << 20));
                tup[pos] = (pk << 32) | (unsigned)d[i];
            }
        }
    }
}

// K3: XCD-affine bucket sweep. Per bucket: 512 slot-chunks (midpoints) +
// 64 copy-chunks (the bucket's own 1024 node rows -> L2 hits).
__global__ __launch_bounds__(256) void main_kernel(
        const f32x4* __restrict__ x4,
        const u64* __restrict__ tup, const int* __restrict__ cursor,
        f32x4* __restrict__ out4,
        int N, int NB, int MBlk) {
    const unsigned b = blockIdx.x;
    if (b >= (unsigned)MBlk) return;
    const int xcd = b & 7;
    const int seq = b >> 3;
    const int bucket = xcd + 8 * (seq / BPB);
    if (bucket >= NB) return;
    const int r = seq % BPB;
    const int lane = threadIdx.x & 31;
    const int g = threadIdx.x >> 5;

    if (r < SPB) {
        // ---- midpoint slot-chunk ----
        const int cnt = cursor[bucket] - bucket * SLOTS;  // fill count
        const int si0 = r * 16 + g * 2;
        if (si0 >= cnt) return;
        const int p0 = bucket * SLOTS + si0;
        const int nbase = bucket << BSHIFT;

        const u64 t0 = tup[p0];
        const bool have1 = (si0 + 1) < cnt;
        const u64 t1 = have1 ? tup[p0 + 1] : 0;

        const int d0 = (int)(t0 & 0xffffffffu);
        const int pk0 = (int)(t0 >> 32);
        const int s0 = nbase | (pk0 >> 20);
        const int e0 = pk0 & 0xFFFFF;

        f32x4 a0 = x4[(size_t)s0 * F4 + lane];    // src: L2-resident bucket
        f32x4 b0 = x4[(size_t)d0 * F4 + lane];    // dst: random

        if (have1) {
            const int d1 = (int)(t1 & 0xffffffffu);
            const int pk1 = (int)(t1 >> 32);
            const int s1 = nbase | (pk1 >> 20);
            const int e1 = pk1 & 0xFFFFF;
            f32x4 a1 = x4[(size_t)s1 * F4 + lane];
            f32x4 b1 = x4[(size_t)d1 * F4 + lane];
            nt_store4(0.5f * (a0 + b0), &out4[(size_t)(N + e0) * F4 + lane]);
            nt_store4(0.5f * (a1 + b1), &out4[(size_t)(N + e1) * F4 + lane]);
        } else {
            nt_store4(0.5f * (a0 + b0), &out4[(size_t)(N + e0) * F4 + lane]);
        }
    } else {
        // ---- copy-chunk: this bucket's own node rows (L2-hot) ----
        const int cr = r - SPB;                   // 0..63
        const long long row0 = ((long long)bucket << BSHIFT) + cr * 16 + g * 2;
        if (row0 < N) {
            f32x4 v0 = x4[row0 * F4 + lane];
            nt_store4(v0, &out4[row0 * F4 + lane]);
        }
        const long long row1 = row0 + 1;
        if (row1 < N) {
            f32x4 v1 = x4[row1 * F4 + lane];
            nt_store4(v1, &out4[row1 * F4 + lane]);
        }
    }
}

extern "C" void kernel_launch(void* const* d_in, const int* in_sizes, int n_in,
                              void* d_out, int out_size, void* d_ws, size_t ws_size,
                              hipStream_t stream) {
    const float* x = (const float*)d_in[0];
    const int* ei = (const int*)d_in[1];

    const int N = in_sizes[0] / F;                 // 100000
    const int E = in_sizes[1] / 2;                 // 600000
    const int T = (E > 2) ? (E - 2 + 2) / 3 : 0;   // ceil((E-2)/3)
    const int M = 3 * E + 3 * T;

    const int* ei0 = ei;
    const int* ei1 = ei + E;

    float* out = (float*)d_out;
    float* r0 = out + (size_t)(N + E) * F;
    float* r1 = r0 + M;

    // ws layout: [0..4095] cursors | [4096..] u64 slot array
    int* cursor = (int*)d_ws;
    u64* tup = (u64*)((char*)d_ws + 4096);

    const int NB = (N + (1 << BSHIFT) - 1) >> BSHIFT;   // 98
    const int NBpad = (NB + 7) & ~7;                    // 104
    const int MBlk = NBpad * BPB;                       // 59904 blocks

    init_kernel<<<1, 128, 0, stream>>>(cursor, NB);
    scatter_kernel<<<(E + CHUNK - 1) / CHUNK, 256, 0, stream>>>(
        ei0, ei1, cursor, tup, r0, r1, N, E, 3 * T, NB);
    main_kernel<<<MBlk, 256, 0, stream>>>(
        (const f32x4*)x, tup, cursor, (f32x4*)out, N, NB, MBlk);
}